// Round 12
// baseline (284.006 us; speedup 1.0000x reference)
//
// v9 — k_sink: 6-deep row pipeline, groups rebalanced (OT 4x64, self 8x32);
// GEMM: nontemporal P-tile stores (write-amplification probe). Rest unchanged from v8.
#include <hip/hip_runtime.h>
#include <hip/hip_fp16.h>

#define NP 1500
#define DD 300
#define DP 320              // padded dims (mult of 64 for BK=64 steps)
#define VSZ 1536            // vector stride per batch (floats)
#define NB 4
#define TILE 16384          // halfs per 128x128 tile
#define TSZ (1536*1536)     // halfs per P slot
#define OTB 64              // blocks per OT group
#define SELFB 32            // blocks per self group
#define KADD 1.8283051e-8f  // eps * ln(1500), eps = (5e-5)^2
#define PADVAL (-60000.0f)
#define SCALE 256.0f
#define SCALE2INV (1.0f/65536.0f)

typedef _Float16 f16x8 __attribute__((ext_vector_type(8)));
typedef float f32x4 __attribute__((ext_vector_type(4)));
typedef unsigned int u32x4 __attribute__((ext_vector_type(4)));

__global__ void k_zero(float* p, int n){
    int i = blockIdx.x*blockDim.x + threadIdx.x;
    if (i < n) p[i] = 0.f;
}

// ---- deterministic column sums (2-stage, no float atomics) ----
__global__ __launch_bounds__(256) void k_colsum_p1(const float* __restrict__ x, const float* __restrict__ y,
                                                   float* __restrict__ partial){
    int rc = blockIdx.x, b = blockIdx.y, src = blockIdx.z;
    const float* in = (src ? y : x) + ((size_t)b*NP + rc*125)*DD;
    int tid = threadIdx.x;
    float s0 = 0.f, s1 = 0.f;
    #pragma unroll 4
    for (int r = 0; r < 125; ++r){
        float v0 = in[r*DD + tid];
        s0 = fmaf(v0, v0, s0);
        if (tid < 44){
            float v1 = in[r*DD + 256 + tid];
            s1 = fmaf(v1, v1, s1);
        }
    }
    float* po = partial + (((size_t)rc*NB + b)*2 + src)*DD;
    po[tid] = s0;
    if (tid < 44) po[256 + tid] = s1;
}

__global__ void k_colsum_p2(const float* __restrict__ partial,
                            float* __restrict__ csx, float* __restrict__ csy){
    int idx = blockIdx.x*256 + threadIdx.x;
    if (idx >= NB*2*DD) return;
    int c = idx % DD; int t = idx / DD; int src = t & 1; int b = t >> 1;
    float s = 0.f;
    #pragma unroll
    for (int rc = 0; rc < 12; ++rc)
        s += partial[(((size_t)rc*NB + b)*2 + src)*DD + c];
    (src ? csy : csx)[b*DD + c] = s;
}

// ---- fused normalize (fp16, scaled) + row-norm init of small vectors ----
__global__ __launch_bounds__(256) void k_normrow(const float* __restrict__ x, const float* __restrict__ y,
        const float* __restrict__ csx, const float* __restrict__ csy,
        __half* __restrict__ pxh, __half* __restrict__ pyh,
        float* __restrict__ psxx0, float* __restrict__ uvv, float* __restrict__ psyy0){
    int i = blockIdx.x, b = blockIdx.y, src = blockIdx.z;
    const float* in = (src ? y : x) + ((size_t)b*NP + i)*DD;
    const float* cs = (src ? csy : csx) + b*DD;
    __half* oph = (src ? pyh : pxh) + ((size_t)b*NP + i)*DP;
    int tid = threadIdx.x;
    float s;
    {
        float u = in[tid];
        float vu = u*u / cs[tid];
        oph[tid] = __float2half(vu * SCALE);
        s = vu*vu;
    }
    if (tid < 64){
        int c = 256 + tid;
        float h = 0.f, vu = 0.f;
        if (c < DD){
            float u = in[c];
            vu = u*u / cs[c];
            h = vu * SCALE;
        }
        oph[c] = __float2half(h);
        s += vu*vu;
    }
    #pragma unroll
    for (int o2 = 1; o2 < 64; o2 <<= 1) s += __shfl_xor(s, o2, 64);
    __shared__ float sred[4];
    if ((tid & 63) == 0) sred[tid>>6] = s;
    __syncthreads();
    if (tid == 0){
        float val = 0.5f*(sred[0]+sred[1]+sred[2]+sred[3]);
        int o = b*VSZ + i;
        if (src){ uvv[o] = val; psyy0[o] = val; }
        else    { psxx0[o] = val; }
    }
}

// ---- MFMA GEMM: BK=64, register prefetch, XOR-swizzled LDS, triangle+transpose,
//      NONTEMPORAL P stores ----
__global__ __launch_bounds__(256) void k_gemm_mfma(const __half* __restrict__ pxh,
                                                   const __half* __restrict__ pyh,
                                                   __half* __restrict__ P){
    int z = blockIdx.z; int b = z/3; int kidx = z - b*3;
    int kind = (kidx==0) ? 0 : ((kidx==1) ? 2 : 3);
    int bx = blockIdx.x, by = blockIdx.y;
    if (kind != 0 && by > bx) return;
    const __half* A = (((kind==0)||(kind==2)) ? pxh : pyh) + (size_t)b*NP*DP;
    const __half* B = (((kind==0)||(kind==3)) ? pyh : pxh) + (size_t)b*NP*DP;

    __shared__ __align__(16) char smem[128*136*2];
    char* ldsA = smem;                  // 128 rows x 64 halfs (128B/row)
    char* ldsB = smem + 16384;
    __half* ldsO = (__half*)smem;       // epilogue: 128 x 136 halfs

    int tid = threadIdx.x;
    int row0 = bx*128, col0 = by*128;
    int lane = tid & 63;
    int w = tid >> 6;
    int wm = (w >> 1)*64, wn = (w & 1)*64;
    int g8 = tid & 7, rw = tid >> 3;
    int lr = lane & 15, cq = lane >> 4;

    f32x4 acc[4][4];
    #pragma unroll
    for (int mi = 0; mi < 4; ++mi)
        #pragma unroll
        for (int ni = 0; ni < 4; ++ni)
            acc[mi][ni] = (f32x4){0.f, 0.f, 0.f, 0.f};

    uint4 va[4], vb[4];
    #pragma unroll
    for (int is = 0; is < 4; ++is){
        int r = rw + is*32;
        int ar = row0 + r; if (ar > NP-1) ar = NP-1;
        int br = col0 + r; if (br > NP-1) br = NP-1;
        va[is] = *(const uint4*)(A + (size_t)ar*DP + g8*8);
        vb[is] = *(const uint4*)(B + (size_t)br*DP + g8*8);
    }
    #pragma unroll
    for (int ks = 0; ks < 5; ++ks){
        if (ks) __syncthreads();
        #pragma unroll
        for (int is = 0; is < 4; ++is){
            int r = rw + is*32;
            int pc = g8 ^ (r & 7);
            *(uint4*)(ldsA + r*128 + pc*16) = va[is];
            *(uint4*)(ldsB + r*128 + pc*16) = vb[is];
        }
        __syncthreads();
        if (ks < 4){
            int k0 = (ks + 1)*64;
            #pragma unroll
            for (int is = 0; is < 4; ++is){
                int r = rw + is*32;
                int ar = row0 + r; if (ar > NP-1) ar = NP-1;
                int br = col0 + r; if (br > NP-1) br = NP-1;
                va[is] = *(const uint4*)(A + (size_t)ar*DP + k0 + g8*8);
                vb[is] = *(const uint4*)(B + (size_t)br*DP + k0 + g8*8);
            }
        }
        f16x8 av[2][4], bv[2][4];
        #pragma unroll
        for (int ksl = 0; ksl < 2; ++ksl){
            int lc = ksl*4 + cq;
            int pc = (lc ^ (lr & 7))*16;
            #pragma unroll
            for (int mi = 0; mi < 4; ++mi)
                av[ksl][mi] = *(const f16x8*)(ldsA + (wm + mi*16 + lr)*128 + pc);
            #pragma unroll
            for (int ni = 0; ni < 4; ++ni)
                bv[ksl][ni] = *(const f16x8*)(ldsB + (wn + ni*16 + lr)*128 + pc);
        }
        #pragma unroll
        for (int ksl = 0; ksl < 2; ++ksl)
            #pragma unroll
            for (int mi = 0; mi < 4; ++mi)
                #pragma unroll
                for (int ni = 0; ni < 4; ++ni)
                    acc[mi][ni] = __builtin_amdgcn_mfma_f32_16x16x32_f16(av[ksl][mi], bv[ksl][ni], acc[mi][ni], 0, 0, 0);
    }

    int cqe = lane >> 4;
    __syncthreads();
    #pragma unroll
    for (int mi = 0; mi < 4; ++mi)
        #pragma unroll
        for (int ni = 0; ni < 4; ++ni){
            int lcol = wn + ni*16 + lr;
            bool colok = (col0 + lcol) < NP;
            #pragma unroll
            for (int v = 0; v < 4; ++v){
                int lrow = wm + mi*16 + cqe*4 + v;
                ldsO[lrow*136 + lcol] = __float2half(colok ? acc[mi][ni][v]*SCALE2INV : PADVAL);
            }
        }
    __syncthreads();
    {
        __half* tileD = P + (size_t)(b*4 + kind)*TSZ + ((size_t)bx*12 + by)*TILE;
        #pragma unroll
        for (int it = 0; it < 8; ++it){
            int e = it*256 + tid;
            int r = e >> 4, q = e & 15;
            u32x4 vv = *(const u32x4*)(ldsO + r*136 + q*8);
            __builtin_nontemporal_store(vv, (u32x4*)(tileD + r*128 + q*8));
        }
    }
    if (kind == 0 || bx != by){
        __syncthreads();
        #pragma unroll
        for (int mi = 0; mi < 4; ++mi)
            #pragma unroll
            for (int ni = 0; ni < 4; ++ni){
                int trow = wn + ni*16 + lr;
                #pragma unroll
                for (int v = 0; v < 4; ++v){
                    int tcol = wm + mi*16 + cqe*4 + v;
                    bool rowok = (row0 + tcol) < NP;
                    ldsO[trow*136 + tcol] = __float2half(rowok ? acc[mi][ni][v]*SCALE2INV : PADVAL);
                }
            }
        __syncthreads();
        int slotT = (kind == 0) ? 1 : kind;
        __half* tileT = P + (size_t)(b*4 + slotT)*TSZ + ((size_t)by*12 + bx)*TILE;
        #pragma unroll
        for (int it = 0; it < 8; ++it){
            int e = it*256 + tid;
            int r = e >> 4, q = e & 15;
            u32x4 vv = *(const u32x4*)(ldsO + r*136 + q*8);
            __builtin_nontemporal_store(vv, (u32x4*)(tileT + r*128 + q*8));
        }
    }
}

// ---- persistent Sinkhorn, 12 block-groups, 6-deep row pipeline ----
__device__ __forceinline__ void groupbar(int* slot, int gsz){
    __syncthreads();
    if (threadIdx.x == 0){
        __hip_atomic_fetch_add(slot, 1, __ATOMIC_RELEASE, __HIP_MEMORY_SCOPE_AGENT);
        while (__hip_atomic_load(slot, __ATOMIC_ACQUIRE, __HIP_MEMORY_SCOPE_AGENT) < gsz)
            __builtin_amdgcn_s_sleep(1);
    }
    __syncthreads();
}

__device__ __forceinline__ void loadvec(const float* __restrict__ v, float4* A0, float4* A1, int lane){
    const float4* a4 = (const float4*)v;
    #pragma unroll
    for (int it = 0; it < 3; ++it){
        int c = lane + it*64, tt = c >> 4, q = c & 15;
        A0[it] = a4[tt*32 + q*2];
        A1[it] = a4[tt*32 + q*2 + 1];
    }
}

__device__ __forceinline__ void loadrow(const __half* __restrict__ rowb, int lane, uint4* pk){
    #pragma unroll
    for (int it = 0; it < 3; ++it){
        int c = lane + it*64, tt = c >> 4, q = c & 15;
        pk[it] = *(const uint4*)(rowb + (size_t)tt*TILE + q*8);
    }
}

__device__ __forceinline__ float redrow(const uint4* pk, const float4* A0, const float4* A1, int lane){
    float m = 3.0e38f;
    #pragma unroll
    for (int it = 0; it < 3; ++it){
        float2 c0 = __half22float2(*(const __half2*)&pk[it].x);
        float2 c1 = __half22float2(*(const __half2*)&pk[it].y);
        float2 c2 = __half22float2(*(const __half2*)&pk[it].z);
        float2 c3 = __half22float2(*(const __half2*)&pk[it].w);
        m = fminf(m, fminf(fminf(A0[it].x - c0.x, A0[it].y - c0.y), fminf(A0[it].z - c1.x, A0[it].w - c1.y)));
        m = fminf(m, fminf(fminf(A1[it].x - c2.x, A1[it].y - c2.y), fminf(A1[it].z - c3.x, A1[it].w - c3.y)));
    }
    #pragma unroll
    for (int o = 1; o < 64; o <<= 1) m = fminf(m, __shfl_xor(m, o, 64));
    return m;
}

#define ROWPTR(PK, i) ((PK) + (size_t)((i) >> 7)*12*TILE + (size_t)((i) & 127)*128)

// One sweep phase, 6-deep pipelined. selfmode: out = 0.5*(in - m - K) vs out = -(m + K).
__device__ __forceinline__ int sweep_phase(const __half* __restrict__ PK,
        const float4* A0, const float4* A1,
        const float* __restrict__ inA, float* __restrict__ outv,
        int selfmode, int gw, int NWV, int lane){
    int ch = 0;
    for (int i0 = gw; i0 < NP; i0 += 6*NWV){
        uint4 pk[6][3];
        #pragma unroll
        for (int k = 0; k < 6; ++k){
            int i = i0 + k*NWV;
            if (i < NP) loadrow(ROWPTR(PK, i), lane, pk[k]);
        }
        #pragma unroll
        for (int k = 0; k < 6; ++k){
            int i = i0 + k*NWV;
            if (i < NP){
                float m = redrow(pk[k], A0, A1, lane);
                if (lane == 0){
                    float nv;
                    if (selfmode){
                        float ov = inA[i];
                        nv = 0.5f*(ov - m - KADD);
                        if (__float_as_uint(nv) != __float_as_uint(ov)) ch = 1;
                    } else {
                        nv = -(m + KADD);
                        if (__float_as_uint(nv) != __float_as_uint(outv[i])) ch = 1;
                    }
                    outv[i] = nv;
                }
            }
        }
    }
    return ch;
}

__global__ __launch_bounds__(256, 2) void k_sink(const __half* __restrict__ P,
        float* __restrict__ fs, float* __restrict__ uvv,
        float* __restrict__ px0, float* __restrict__ px1,
        float* __restrict__ py0, float* __restrict__ py1,
        int* __restrict__ bars, int* __restrict__ flags){
    int tid = threadIdx.x;
    int lane = tid & 63;
    int wid = tid >> 6;
    int blk = (int)blockIdx.x;
    __shared__ int s_ch;
    float4 A0[3], A1[3];

    if (blk < 4*OTB){
        // ---------------- OT group (fs <-> u), batch b ----------------
        int b = blk / OTB, lb = blk - b*OTB;
        int gw = lb*4 + wid;
        const int NWV = OTB*4;
        int* gbarp  = bars + b*64;
        int* gflagp = flags + b*64;
        const __half* P0 = P + (size_t)(b*4 + 0)*TSZ;
        const __half* P1 = P + (size_t)(b*4 + 1)*TSZ;
        float* fsb = fs + b*VSZ;
        float* uvb = uvv + b*VSZ;
        for (int t = 0; t < 30; ++t){
            if (tid == 0) s_ch = 0;
            __syncthreads();
            loadvec(uvb, A0, A1, lane);
            int ch = sweep_phase(P0, A0, A1, (const float*)0, fsb, 0, gw, NWV, lane);
            if (ch) s_ch = 1;
            __syncthreads();
            if (tid == 0 && s_ch) atomicOr(&gflagp[2*t], 1);
            groupbar(&gbarp[2*t], OTB);
            if (tid == 0) s_ch = 0;
            __syncthreads();
            loadvec(fsb, A0, A1, lane);
            ch = sweep_phase(P1, A0, A1, (const float*)0, uvb, 0, gw, NWV, lane);
            if (ch) s_ch = 1;
            __syncthreads();
            if (tid == 0 && s_ch) atomicOr(&gflagp[2*t + 1], 1);
            groupbar(&gbarp[2*t + 1], OTB);
            int fA = __hip_atomic_load(&gflagp[2*t],     __ATOMIC_RELAXED, __HIP_MEMORY_SCOPE_AGENT);
            int fB = __hip_atomic_load(&gflagp[2*t + 1], __ATOMIC_RELAXED, __HIP_MEMORY_SCOPE_AGENT);
            if (fA == 0 && fB == 0) break;
        }
    } else {
        // ---------------- self group (psxx or psyy), ping-pong ----------------
        int sg = blk - 4*OTB;
        int g = sg / SELFB, lb = sg - g*SELFB;
        int gw = lb*4 + wid;
        const int NWV = SELFB*4;
        int b = g >> 1, kind = 2 + (g & 1);
        float* bufA = ((g & 1) ? py0 : px0) + b*VSZ;
        float* bufB = ((g & 1) ? py1 : px1) + b*VSZ;
        int* gbarp  = bars + (4 + g)*64;
        int* gflagp = flags + (4 + g)*64;
        const __half* PK = P + (size_t)(b*4 + kind)*TSZ;
        for (int t = 0; t < 30; ++t){
            if (tid == 0) s_ch = 0;
            __syncthreads();
            loadvec(bufA, A0, A1, lane);
            int ch = sweep_phase(PK, A0, A1, bufA, bufB, 1, gw, NWV, lane);
            if (ch) s_ch = 1;
            __syncthreads();
            if (tid == 0 && s_ch) atomicOr(&gflagp[t], 1);
            groupbar(&gbarp[t], SELFB);
            int fC = __hip_atomic_load(&gflagp[t], __ATOMIC_RELAXED, __HIP_MEMORY_SCOPE_AGENT);
            if (fC == 0) break;              // frozen: bufA == bufB bitwise
            { float* tmp = bufA; bufA = bufB; bufB = tmp; }
        }
        // 30 full iters: last write (t=29) lands in px0/py0; frozen-break leaves both equal.
    }
}

// S = (4/1500) * sum_b,i (psxx + psyy - fs - u)
__global__ void k_final(const float* __restrict__ fs, const float* __restrict__ u,
                        const float* __restrict__ psxx, const float* __restrict__ psyy,
                        float* __restrict__ out){
    __shared__ double red[256];
    double s = 0.0;
    for (int t = threadIdx.x; t < NB*NP; t += 256){
        int b = t / NP, i = t - b*NP; int o = b*VSZ + i;
        s += (double)psxx[o] + (double)psyy[o] - (double)fs[o] - (double)u[o];
    }
    red[threadIdx.x] = s; __syncthreads();
    for (int w = 128; w > 0; w >>= 1){
        if (threadIdx.x < w) red[threadIdx.x] += red[threadIdx.x + w];
        __syncthreads();
    }
    if (threadIdx.x == 0) out[0] = (float)(red[0] * (4.0/1500.0));
}

extern "C" void kernel_launch(void* const* d_in, const int* in_sizes, int n_in,
                              void* d_out, int out_size, void* d_ws, size_t ws_size,
                              hipStream_t stream) {
    const float* x = (const float*)d_in[0];
    const float* y = (const float*)d_in[1];
    float* out = (float*)d_out;

    __half* pxh = (__half*)d_ws;                       // NB*NP*DP halfs
    __half* pyh = pxh + (size_t)NB*NP*DP;
    float* csx = (float*)(pyh + (size_t)NB*NP*DP);
    float* csy = csx + NB*DD;
    float* fs  = csy + NB*DD;
    float* uv  = fs + NB*VSZ;
    float* px0 = uv + NB*VSZ;
    float* px1 = px0 + NB*VSZ;
    float* py0 = px1 + NB*VSZ;
    float* py1 = py0 + NB*VSZ;
    int* bars  = (int*)(py1 + NB*VSZ);                 // 12*64 ints
    int* flags = bars + 12*64;                         // 12*64 ints
    float* partial = (float*)(flags + 12*64);          // 12*NB*2*DD floats
    float* smallEnd = partial + (size_t)12*NB*2*DD;
    size_t pOff = (((size_t)((char*)smallEnd - (char*)d_ws)) + 255) & ~(size_t)255;
    __half* P = (__half*)((char*)d_ws + pOff);         // 16*TSZ halfs = 75.5 MB

    int nzero = (int)(((float*)(flags + 12*64)) - csx);
    k_zero<<<(nzero + 255)/256, 256, 0, stream>>>(csx, nzero);

    k_colsum_p1<<<dim3(12, NB, 2), 256, 0, stream>>>(x, y, partial);
    k_colsum_p2<<<10, 256, 0, stream>>>(partial, csx, csy);

    k_normrow<<<dim3(NP, NB, 2), 256, 0, stream>>>(x, y, csx, csy, pxh, pyh, px0, uv, py0);

    k_gemm_mfma<<<dim3(12, 12, 12), 256, 0, stream>>>(pxh, pyh, P);

    k_sink<<<4*OTB + 8*SELFB, 256, 0, stream>>>(P, fs, uv, px0, px1, py0, py1, bars, flags);

    k_final<<<1, 256, 0, stream>>>(fs, uv, px0, py0, out);
}

// Round 13
// 259.559 us; speedup vs baseline: 1.0942x; 1.0942x over previous
//
// v10 — revert sink to v8 2-deep structure (OT 4x48, self 8x40); threshold freeze
// (|delta| <= 1e-8, deterministic) replaces bitwise; normrow wave-per-row.
// GEMM kept from v9 (BK64 + nontemporal stores).
#include <hip/hip_runtime.h>
#include <hip/hip_fp16.h>

#define NP 1500
#define DD 300
#define DP 320              // padded dims (mult of 64 for BK=64 steps)
#define VSZ 1536            // vector stride per batch (floats)
#define NB 4
#define TILE 16384          // halfs per 128x128 tile
#define TSZ (1536*1536)     // halfs per P slot
#define OTB 48              // blocks per OT group
#define SELFB 40            // blocks per self group
#define KADD 1.8283051e-8f  // eps * ln(1500), eps = (5e-5)^2
#define PADVAL (-60000.0f)
#define SCALE 256.0f
#define SCALE2INV (1.0f/65536.0f)
#define FTHR 1e-8f          // freeze threshold (deterministic; tail error << 6.5e-5)

typedef _Float16 f16x8 __attribute__((ext_vector_type(8)));
typedef float f32x4 __attribute__((ext_vector_type(4)));
typedef unsigned int u32x4 __attribute__((ext_vector_type(4)));

__global__ void k_zero(float* p, int n){
    int i = blockIdx.x*blockDim.x + threadIdx.x;
    if (i < n) p[i] = 0.f;
}

// ---- deterministic column sums (2-stage, no float atomics) ----
__global__ __launch_bounds__(256) void k_colsum_p1(const float* __restrict__ x, const float* __restrict__ y,
                                                   float* __restrict__ partial){
    int rc = blockIdx.x, b = blockIdx.y, src = blockIdx.z;
    const float* in = (src ? y : x) + ((size_t)b*NP + rc*125)*DD;
    int tid = threadIdx.x;
    float s0 = 0.f, s1 = 0.f;
    #pragma unroll 4
    for (int r = 0; r < 125; ++r){
        float v0 = in[r*DD + tid];
        s0 = fmaf(v0, v0, s0);
        if (tid < 44){
            float v1 = in[r*DD + 256 + tid];
            s1 = fmaf(v1, v1, s1);
        }
    }
    float* po = partial + (((size_t)rc*NB + b)*2 + src)*DD;
    po[tid] = s0;
    if (tid < 44) po[256 + tid] = s1;
}

__global__ void k_colsum_p2(const float* __restrict__ partial,
                            float* __restrict__ csx, float* __restrict__ csy){
    int idx = blockIdx.x*256 + threadIdx.x;
    if (idx >= NB*2*DD) return;
    int c = idx % DD; int t = idx / DD; int src = t & 1; int b = t >> 1;
    float s = 0.f;
    #pragma unroll
    for (int rc = 0; rc < 12; ++rc)
        s += partial[(((size_t)rc*NB + b)*2 + src)*DD + c];
    (src ? csy : csx)[b*DD + c] = s;
}

// ---- fused normalize (fp16, scaled) + row-norm init: one wave per row ----
__global__ __launch_bounds__(256) void k_normrow(const float* __restrict__ x, const float* __restrict__ y,
        const float* __restrict__ csx, const float* __restrict__ csy,
        __half* __restrict__ pxh, __half* __restrict__ pyh,
        float* __restrict__ psxx0, float* __restrict__ uvv, float* __restrict__ psyy0){
    int gw = ((int)blockIdx.x*256 + threadIdx.x) >> 6;
    int lane = threadIdx.x & 63;
    int src = (gw >= NB*NP) ? 1 : 0;
    int rem = gw - src*NB*NP;
    int b = rem / NP, i = rem - b*NP;
    const float* in = (src ? y : x) + ((size_t)b*NP + i)*DD;
    const float* cs = (src ? csy : csx) + b*DD;
    __half* oph = (src ? pyh : pxh) + ((size_t)b*NP + i)*DP;
    float s = 0.f;
    #pragma unroll
    for (int it = 0; it < 5; ++it){
        int c = lane + it*64;
        float vu = 0.f, hv = 0.f;
        if (c < DD){
            float u = in[c];
            vu = u*u / cs[c];
            hv = vu * SCALE;
        }
        oph[c] = __float2half(hv);
        s = fmaf(vu, vu, s);
    }
    #pragma unroll
    for (int o2 = 1; o2 < 64; o2 <<= 1) s += __shfl_xor(s, o2, 64);
    if (lane == 0){
        float val = 0.5f * s;
        int o = b*VSZ + i;
        if (src){ uvv[o] = val; psyy0[o] = val; }
        else    { psxx0[o] = val; }
    }
}

// ---- MFMA GEMM: BK=64, register prefetch, XOR-swizzled LDS, triangle+transpose,
//      nontemporal P stores (unchanged from v9) ----
__global__ __launch_bounds__(256) void k_gemm_mfma(const __half* __restrict__ pxh,
                                                   const __half* __restrict__ pyh,
                                                   __half* __restrict__ P){
    int z = blockIdx.z; int b = z/3; int kidx = z - b*3;
    int kind = (kidx==0) ? 0 : ((kidx==1) ? 2 : 3);
    int bx = blockIdx.x, by = blockIdx.y;
    if (kind != 0 && by > bx) return;
    const __half* A = (((kind==0)||(kind==2)) ? pxh : pyh) + (size_t)b*NP*DP;
    const __half* B = (((kind==0)||(kind==3)) ? pyh : pxh) + (size_t)b*NP*DP;

    __shared__ __align__(16) char smem[128*136*2];
    char* ldsA = smem;                  // 128 rows x 64 halfs (128B/row)
    char* ldsB = smem + 16384;
    __half* ldsO = (__half*)smem;       // epilogue: 128 x 136 halfs

    int tid = threadIdx.x;
    int row0 = bx*128, col0 = by*128;
    int lane = tid & 63;
    int w = tid >> 6;
    int wm = (w >> 1)*64, wn = (w & 1)*64;
    int g8 = tid & 7, rw = tid >> 3;
    int lr = lane & 15, cq = lane >> 4;

    f32x4 acc[4][4];
    #pragma unroll
    for (int mi = 0; mi < 4; ++mi)
        #pragma unroll
        for (int ni = 0; ni < 4; ++ni)
            acc[mi][ni] = (f32x4){0.f, 0.f, 0.f, 0.f};

    uint4 va[4], vb[4];
    #pragma unroll
    for (int is = 0; is < 4; ++is){
        int r = rw + is*32;
        int ar = row0 + r; if (ar > NP-1) ar = NP-1;
        int br = col0 + r; if (br > NP-1) br = NP-1;
        va[is] = *(const uint4*)(A + (size_t)ar*DP + g8*8);
        vb[is] = *(const uint4*)(B + (size_t)br*DP + g8*8);
    }
    #pragma unroll
    for (int ks = 0; ks < 5; ++ks){
        if (ks) __syncthreads();
        #pragma unroll
        for (int is = 0; is < 4; ++is){
            int r = rw + is*32;
            int pc = g8 ^ (r & 7);
            *(uint4*)(ldsA + r*128 + pc*16) = va[is];
            *(uint4*)(ldsB + r*128 + pc*16) = vb[is];
        }
        __syncthreads();
        if (ks < 4){
            int k0 = (ks + 1)*64;
            #pragma unroll
            for (int is = 0; is < 4; ++is){
                int r = rw + is*32;
                int ar = row0 + r; if (ar > NP-1) ar = NP-1;
                int br = col0 + r; if (br > NP-1) br = NP-1;
                va[is] = *(const uint4*)(A + (size_t)ar*DP + k0 + g8*8);
                vb[is] = *(const uint4*)(B + (size_t)br*DP + k0 + g8*8);
            }
        }
        f16x8 av[2][4], bv[2][4];
        #pragma unroll
        for (int ksl = 0; ksl < 2; ++ksl){
            int lc = ksl*4 + cq;
            int pc = (lc ^ (lr & 7))*16;
            #pragma unroll
            for (int mi = 0; mi < 4; ++mi)
                av[ksl][mi] = *(const f16x8*)(ldsA + (wm + mi*16 + lr)*128 + pc);
            #pragma unroll
            for (int ni = 0; ni < 4; ++ni)
                bv[ksl][ni] = *(const f16x8*)(ldsB + (wn + ni*16 + lr)*128 + pc);
        }
        #pragma unroll
        for (int ksl = 0; ksl < 2; ++ksl)
            #pragma unroll
            for (int mi = 0; mi < 4; ++mi)
                #pragma unroll
                for (int ni = 0; ni < 4; ++ni)
                    acc[mi][ni] = __builtin_amdgcn_mfma_f32_16x16x32_f16(av[ksl][mi], bv[ksl][ni], acc[mi][ni], 0, 0, 0);
    }

    int cqe = lane >> 4;
    __syncthreads();
    #pragma unroll
    for (int mi = 0; mi < 4; ++mi)
        #pragma unroll
        for (int ni = 0; ni < 4; ++ni){
            int lcol = wn + ni*16 + lr;
            bool colok = (col0 + lcol) < NP;
            #pragma unroll
            for (int v = 0; v < 4; ++v){
                int lrow = wm + mi*16 + cqe*4 + v;
                ldsO[lrow*136 + lcol] = __float2half(colok ? acc[mi][ni][v]*SCALE2INV : PADVAL);
            }
        }
    __syncthreads();
    {
        __half* tileD = P + (size_t)(b*4 + kind)*TSZ + ((size_t)bx*12 + by)*TILE;
        #pragma unroll
        for (int it = 0; it < 8; ++it){
            int e = it*256 + tid;
            int r = e >> 4, q = e & 15;
            u32x4 vv = *(const u32x4*)(ldsO + r*136 + q*8);
            __builtin_nontemporal_store(vv, (u32x4*)(tileD + r*128 + q*8));
        }
    }
    if (kind == 0 || bx != by){
        __syncthreads();
        #pragma unroll
        for (int mi = 0; mi < 4; ++mi)
            #pragma unroll
            for (int ni = 0; ni < 4; ++ni){
                int trow = wn + ni*16 + lr;
                #pragma unroll
                for (int v = 0; v < 4; ++v){
                    int tcol = wm + mi*16 + cqe*4 + v;
                    bool rowok = (row0 + tcol) < NP;
                    ldsO[trow*136 + tcol] = __float2half(rowok ? acc[mi][ni][v]*SCALE2INV : PADVAL);
                }
            }
        __syncthreads();
        int slotT = (kind == 0) ? 1 : kind;
        __half* tileT = P + (size_t)(b*4 + slotT)*TSZ + ((size_t)by*12 + bx)*TILE;
        #pragma unroll
        for (int it = 0; it < 8; ++it){
            int e = it*256 + tid;
            int r = e >> 4, q = e & 15;
            u32x4 vv = *(const u32x4*)(ldsO + r*136 + q*8);
            __builtin_nontemporal_store(vv, (u32x4*)(tileT + r*128 + q*8));
        }
    }
}

// ---- persistent Sinkhorn, 12 independent block-groups, 2-row pipeline, threshold freeze ----
__device__ __forceinline__ void groupbar(int* slot, int gsz){
    __syncthreads();
    if (threadIdx.x == 0){
        __hip_atomic_fetch_add(slot, 1, __ATOMIC_RELEASE, __HIP_MEMORY_SCOPE_AGENT);
        while (__hip_atomic_load(slot, __ATOMIC_ACQUIRE, __HIP_MEMORY_SCOPE_AGENT) < gsz)
            __builtin_amdgcn_s_sleep(1);
    }
    __syncthreads();
}

__device__ __forceinline__ void loadvec(const float* __restrict__ v, float4* A0, float4* A1, int lane){
    const float4* a4 = (const float4*)v;
    #pragma unroll
    for (int it = 0; it < 3; ++it){
        int c = lane + it*64, tt = c >> 4, q = c & 15;
        A0[it] = a4[tt*32 + q*2];
        A1[it] = a4[tt*32 + q*2 + 1];
    }
}

__device__ __forceinline__ void loadrow(const __half* __restrict__ rowb, int lane, uint4* pk){
    #pragma unroll
    for (int it = 0; it < 3; ++it){
        int c = lane + it*64, tt = c >> 4, q = c & 15;
        pk[it] = *(const uint4*)(rowb + (size_t)tt*TILE + q*8);
    }
}

__device__ __forceinline__ float redrow(const uint4* pk, const float4* A0, const float4* A1, int lane){
    float m = 3.0e38f;
    #pragma unroll
    for (int it = 0; it < 3; ++it){
        float2 c0 = __half22float2(*(const __half2*)&pk[it].x);
        float2 c1 = __half22float2(*(const __half2*)&pk[it].y);
        float2 c2 = __half22float2(*(const __half2*)&pk[it].z);
        float2 c3 = __half22float2(*(const __half2*)&pk[it].w);
        m = fminf(m, fminf(fminf(A0[it].x - c0.x, A0[it].y - c0.y), fminf(A0[it].z - c1.x, A0[it].w - c1.y)));
        m = fminf(m, fminf(fminf(A1[it].x - c2.x, A1[it].y - c2.y), fminf(A1[it].z - c3.x, A1[it].w - c3.y)));
    }
    #pragma unroll
    for (int o = 1; o < 64; o <<= 1) m = fminf(m, __shfl_xor(m, o, 64));
    return m;
}

#define ROWPTR(PK, i) ((PK) + (size_t)((i) >> 7)*12*TILE + (size_t)((i) & 127)*128)

__global__ __launch_bounds__(256, 2) void k_sink(const __half* __restrict__ P,
        float* __restrict__ fs, float* __restrict__ uvv,
        float* __restrict__ px0, float* __restrict__ px1,
        float* __restrict__ py0, float* __restrict__ py1,
        int* __restrict__ bars, int* __restrict__ flags){
    int tid = threadIdx.x;
    int lane = tid & 63;
    int wid = tid >> 6;
    int blk = (int)blockIdx.x;
    __shared__ int s_ch;
    float4 A0[3], A1[3];
    uint4 pk0[3], pk1[3];

    if (blk < 4*OTB){
        // ---------------- OT group (fs <-> u), batch b ----------------
        int b = blk / OTB, lb = blk - b*OTB;
        int gw = lb*4 + wid;
        const int NWV = OTB*4;
        int* gbarp  = bars + b*64;
        int* gflagp = flags + b*64;
        const __half* P0 = P + (size_t)(b*4 + 0)*TSZ;
        const __half* P1 = P + (size_t)(b*4 + 1)*TSZ;
        float* fsb = fs + b*VSZ;
        float* uvb = uvv + b*VSZ;
        for (int t = 0; t < 30; ++t){
            // phase A: fs_i = -(min_j(u_j - P0_ij) + K)
            if (tid == 0) s_ch = 0;
            __syncthreads();
            {
                int ch = 0;
                loadvec(uvb, A0, A1, lane);
                for (int i = gw; i < NP; i += 2*NWV){
                    int i2 = i + NWV;
                    loadrow(ROWPTR(P0, i), lane, pk0);
                    if (i2 < NP) loadrow(ROWPTR(P0, i2), lane, pk1);
                    float m = redrow(pk0, A0, A1, lane);
                    if (lane == 0){
                        float nv = -(m + KADD);
                        if (fabsf(nv - fsb[i]) > FTHR) ch = 1;
                        fsb[i] = nv;
                    }
                    if (i2 < NP){
                        float m2 = redrow(pk1, A0, A1, lane);
                        if (lane == 0){
                            float nv = -(m2 + KADD);
                            if (fabsf(nv - fsb[i2]) > FTHR) ch = 1;
                            fsb[i2] = nv;
                        }
                    }
                }
                if (ch) s_ch = 1;
            }
            __syncthreads();
            if (tid == 0 && s_ch) atomicOr(&gflagp[2*t], 1);
            groupbar(&gbarp[2*t], OTB);
            // phase B: u_j = -(min_i(fs_i - P1_ji) + K)
            if (tid == 0) s_ch = 0;
            __syncthreads();
            {
                int ch = 0;
                loadvec(fsb, A0, A1, lane);
                for (int i = gw; i < NP; i += 2*NWV){
                    int i2 = i + NWV;
                    loadrow(ROWPTR(P1, i), lane, pk0);
                    if (i2 < NP) loadrow(ROWPTR(P1, i2), lane, pk1);
                    float m = redrow(pk0, A0, A1, lane);
                    if (lane == 0){
                        float nv = -(m + KADD);
                        if (fabsf(nv - uvb[i]) > FTHR) ch = 1;
                        uvb[i] = nv;
                    }
                    if (i2 < NP){
                        float m2 = redrow(pk1, A0, A1, lane);
                        if (lane == 0){
                            float nv = -(m2 + KADD);
                            if (fabsf(nv - uvb[i2]) > FTHR) ch = 1;
                            uvb[i2] = nv;
                        }
                    }
                }
                if (ch) s_ch = 1;
            }
            __syncthreads();
            if (tid == 0 && s_ch) atomicOr(&gflagp[2*t + 1], 1);
            groupbar(&gbarp[2*t + 1], OTB);
            int fA = __hip_atomic_load(&gflagp[2*t],     __ATOMIC_RELAXED, __HIP_MEMORY_SCOPE_AGENT);
            int fB = __hip_atomic_load(&gflagp[2*t + 1], __ATOMIC_RELAXED, __HIP_MEMORY_SCOPE_AGENT);
            if (fA == 0 && fB == 0) break;
        }
    } else {
        // ---------------- self group (psxx or psyy), ping-pong ----------------
        int sg = blk - 4*OTB;
        int g = sg / SELFB, lb = sg - g*SELFB;
        int gw = lb*4 + wid;
        const int NWV = SELFB*4;
        int b = g >> 1, kind = 2 + (g & 1);
        float* bufA = ((g & 1) ? py0 : px0) + b*VSZ;
        float* bufB = ((g & 1) ? py1 : px1) + b*VSZ;
        int* gbarp  = bars + (4 + g)*64;
        int* gflagp = flags + (4 + g)*64;
        const __half* PK = P + (size_t)(b*4 + kind)*TSZ;
        for (int t = 0; t < 30; ++t){
            if (tid == 0) s_ch = 0;
            __syncthreads();
            {
                int ch = 0;
                loadvec(bufA, A0, A1, lane);
                for (int i = gw; i < NP; i += 2*NWV){
                    int i2 = i + NWV;
                    loadrow(ROWPTR(PK, i), lane, pk0);
                    if (i2 < NP) loadrow(ROWPTR(PK, i2), lane, pk1);
                    float m = redrow(pk0, A0, A1, lane);
                    if (lane == 0){
                        float ov = bufA[i];
                        float nv = 0.5f*(ov - m - KADD);
                        if (fabsf(nv - ov) > FTHR) ch = 1;
                        bufB[i] = nv;
                    }
                    if (i2 < NP){
                        float m2 = redrow(pk1, A0, A1, lane);
                        if (lane == 0){
                            float ov = bufA[i2];
                            float nv = 0.5f*(ov - m2 - KADD);
                            if (fabsf(nv - ov) > FTHR) ch = 1;
                            bufB[i2] = nv;
                        }
                    }
                }
                if (ch) s_ch = 1;
            }
            __syncthreads();
            if (tid == 0 && s_ch) atomicOr(&gflagp[t], 1);
            groupbar(&gbarp[t], SELFB);
            int fC = __hip_atomic_load(&gflagp[t], __ATOMIC_RELAXED, __HIP_MEMORY_SCOPE_AGENT);
            if (fC == 0) break;              // frozen: |bufB - bufA| <= FTHR everywhere
            { float* tmp = bufA; bufA = bufB; bufB = tmp; }
        }
        // full 30 iters: last write (t=29, odd) lands in px0/py0; frozen-break: buffers equal within FTHR.
    }
}

// S = (4/1500) * sum_b,i (psxx + psyy - fs - u)
__global__ void k_final(const float* __restrict__ fs, const float* __restrict__ u,
                        const float* __restrict__ psxx, const float* __restrict__ psyy,
                        float* __restrict__ out){
    __shared__ double red[256];
    double s = 0.0;
    for (int t = threadIdx.x; t < NB*NP; t += 256){
        int b = t / NP, i = t - b*NP; int o = b*VSZ + i;
        s += (double)psxx[o] + (double)psyy[o] - (double)fs[o] - (double)u[o];
    }
    red[threadIdx.x] = s; __syncthreads();
    for (int w = 128; w > 0; w >>= 1){
        if (threadIdx.x < w) red[threadIdx.x] += red[threadIdx.x + w];
        __syncthreads();
    }
    if (threadIdx.x == 0) out[0] = (float)(red[0] * (4.0/1500.0));
}

extern "C" void kernel_launch(void* const* d_in, const int* in_sizes, int n_in,
                              void* d_out, int out_size, void* d_ws, size_t ws_size,
                              hipStream_t stream) {
    const float* x = (const float*)d_in[0];
    const float* y = (const float*)d_in[1];
    float* out = (float*)d_out;

    __half* pxh = (__half*)d_ws;                       // NB*NP*DP halfs
    __half* pyh = pxh + (size_t)NB*NP*DP;
    float* csx = (float*)(pyh + (size_t)NB*NP*DP);
    float* csy = csx + NB*DD;
    float* fs  = csy + NB*DD;
    float* uv  = fs + NB*VSZ;
    float* px0 = uv + NB*VSZ;
    float* px1 = px0 + NB*VSZ;
    float* py0 = px1 + NB*VSZ;
    float* py1 = py0 + NB*VSZ;
    int* bars  = (int*)(py1 + NB*VSZ);                 // 12*64 ints
    int* flags = bars + 12*64;                         // 12*64 ints
    float* partial = (float*)(flags + 12*64);          // 12*NB*2*DD floats
    float* smallEnd = partial + (size_t)12*NB*2*DD;
    size_t pOff = (((size_t)((char*)smallEnd - (char*)d_ws)) + 255) & ~(size_t)255;
    __half* P = (__half*)((char*)d_ws + pOff);         // 16*TSZ halfs = 75.5 MB

    int nzero = (int)(((float*)(flags + 12*64)) - csx);
    k_zero<<<(nzero + 255)/256, 256, 0, stream>>>(csx, nzero);

    k_colsum_p1<<<dim3(12, NB, 2), 256, 0, stream>>>(x, y, partial);
    k_colsum_p2<<<10, 256, 0, stream>>>(partial, csx, csy);

    k_normrow<<<3000, 256, 0, stream>>>(x, y, csx, csy, pxh, pyh, px0, uv, py0);

    k_gemm_mfma<<<dim3(12, 12, 12), 256, 0, stream>>>(pxh, pyh, P);

    k_sink<<<4*OTB + 8*SELFB, 256, 0, stream>>>(P, fs, uv, px0, px1, py0, py1, bars, flags);

    k_final<<<1, 256, 0, stream>>>(fs, uv, px0, py0, out);
}

// Round 15
// 219.289 us; speedup vs baseline: 1.2951x; 1.1836x over previous
//
// v11 — k_sink regrouped: 12 groups x 8 blocks x 1024 threads (8-arrival barriers,
// __syncthreads intra-block). 2-deep pipeline + threshold freeze unchanged from v10.
// GEMM unchanged (BK64 + nontemporal). [resubmission after UnresponsiveContainer]
#include <hip/hip_runtime.h>
#include <hip/hip_fp16.h>

#define NP 1500
#define DD 300
#define DP 320              // padded dims (mult of 64 for BK=64 steps)
#define VSZ 1536            // vector stride per batch (floats)
#define NB 4
#define TILE 16384          // halfs per 128x128 tile
#define TSZ (1536*1536)     // halfs per P slot
#define OTB 8               // blocks per OT group (1024 threads each)
#define SELFB 8             // blocks per self group
#define KADD 1.8283051e-8f  // eps * ln(1500), eps = (5e-5)^2
#define PADVAL (-60000.0f)
#define SCALE 256.0f
#define SCALE2INV (1.0f/65536.0f)
#define FTHR 1e-8f          // freeze threshold (deterministic; tail error << 6.5e-5)

typedef _Float16 f16x8 __attribute__((ext_vector_type(8)));
typedef float f32x4 __attribute__((ext_vector_type(4)));
typedef unsigned int u32x4 __attribute__((ext_vector_type(4)));

__global__ void k_zero(float* p, int n){
    int i = blockIdx.x*blockDim.x + threadIdx.x;
    if (i < n) p[i] = 0.f;
}

// ---- deterministic column sums (2-stage, no float atomics) ----
__global__ __launch_bounds__(256) void k_colsum_p1(const float* __restrict__ x, const float* __restrict__ y,
                                                   float* __restrict__ partial){
    int rc = blockIdx.x, b = blockIdx.y, src = blockIdx.z;
    const float* in = (src ? y : x) + ((size_t)b*NP + rc*125)*DD;
    int tid = threadIdx.x;
    float s0 = 0.f, s1 = 0.f;
    #pragma unroll 4
    for (int r = 0; r < 125; ++r){
        float v0 = in[r*DD + tid];
        s0 = fmaf(v0, v0, s0);
        if (tid < 44){
            float v1 = in[r*DD + 256 + tid];
            s1 = fmaf(v1, v1, s1);
        }
    }
    float* po = partial + (((size_t)rc*NB + b)*2 + src)*DD;
    po[tid] = s0;
    if (tid < 44) po[256 + tid] = s1;
}

__global__ void k_colsum_p2(const float* __restrict__ partial,
                            float* __restrict__ csx, float* __restrict__ csy){
    int idx = blockIdx.x*256 + threadIdx.x;
    if (idx >= NB*2*DD) return;
    int c = idx % DD; int t = idx / DD; int src = t & 1; int b = t >> 1;
    float s = 0.f;
    #pragma unroll
    for (int rc = 0; rc < 12; ++rc)
        s += partial[(((size_t)rc*NB + b)*2 + src)*DD + c];
    (src ? csy : csx)[b*DD + c] = s;
}

// ---- fused normalize (fp16, scaled) + row-norm init: one wave per row ----
__global__ __launch_bounds__(256) void k_normrow(const float* __restrict__ x, const float* __restrict__ y,
        const float* __restrict__ csx, const float* __restrict__ csy,
        __half* __restrict__ pxh, __half* __restrict__ pyh,
        float* __restrict__ psxx0, float* __restrict__ uvv, float* __restrict__ psyy0){
    int gw = ((int)blockIdx.x*256 + threadIdx.x) >> 6;
    int lane = threadIdx.x & 63;
    int src = (gw >= NB*NP) ? 1 : 0;
    int rem = gw - src*NB*NP;
    int b = rem / NP, i = rem - b*NP;
    const float* in = (src ? y : x) + ((size_t)b*NP + i)*DD;
    const float* cs = (src ? csy : csx) + b*DD;
    __half* oph = (src ? pyh : pxh) + ((size_t)b*NP + i)*DP;
    float s = 0.f;
    #pragma unroll
    for (int it = 0; it < 5; ++it){
        int c = lane + it*64;
        float vu = 0.f, hv = 0.f;
        if (c < DD){
            float u = in[c];
            vu = u*u / cs[c];
            hv = vu * SCALE;
        }
        oph[c] = __float2half(hv);
        s = fmaf(vu, vu, s);
    }
    #pragma unroll
    for (int o2 = 1; o2 < 64; o2 <<= 1) s += __shfl_xor(s, o2, 64);
    if (lane == 0){
        float val = 0.5f * s;
        int o = b*VSZ + i;
        if (src){ uvv[o] = val; psyy0[o] = val; }
        else    { psxx0[o] = val; }
    }
}

// ---- MFMA GEMM: BK=64, register prefetch, XOR-swizzled LDS, triangle+transpose,
//      nontemporal P stores (unchanged) ----
__global__ __launch_bounds__(256) void k_gemm_mfma(const __half* __restrict__ pxh,
                                                   const __half* __restrict__ pyh,
                                                   __half* __restrict__ P){
    int z = blockIdx.z; int b = z/3; int kidx = z - b*3;
    int kind = (kidx==0) ? 0 : ((kidx==1) ? 2 : 3);
    int bx = blockIdx.x, by = blockIdx.y;
    if (kind != 0 && by > bx) return;
    const __half* A = (((kind==0)||(kind==2)) ? pxh : pyh) + (size_t)b*NP*DP;
    const __half* B = (((kind==0)||(kind==3)) ? pyh : pxh) + (size_t)b*NP*DP;

    __shared__ __align__(16) char smem[128*136*2];
    char* ldsA = smem;                  // 128 rows x 64 halfs (128B/row)
    char* ldsB = smem + 16384;
    __half* ldsO = (__half*)smem;       // epilogue: 128 x 136 halfs

    int tid = threadIdx.x;
    int row0 = bx*128, col0 = by*128;
    int lane = tid & 63;
    int w = tid >> 6;
    int wm = (w >> 1)*64, wn = (w & 1)*64;
    int g8 = tid & 7, rw = tid >> 3;
    int lr = lane & 15, cq = lane >> 4;

    f32x4 acc[4][4];
    #pragma unroll
    for (int mi = 0; mi < 4; ++mi)
        #pragma unroll
        for (int ni = 0; ni < 4; ++ni)
            acc[mi][ni] = (f32x4){0.f, 0.f, 0.f, 0.f};

    uint4 va[4], vb[4];
    #pragma unroll
    for (int is = 0; is < 4; ++is){
        int r = rw + is*32;
        int ar = row0 + r; if (ar > NP-1) ar = NP-1;
        int br = col0 + r; if (br > NP-1) br = NP-1;
        va[is] = *(const uint4*)(A + (size_t)ar*DP + g8*8);
        vb[is] = *(const uint4*)(B + (size_t)br*DP + g8*8);
    }
    #pragma unroll
    for (int ks = 0; ks < 5; ++ks){
        if (ks) __syncthreads();
        #pragma unroll
        for (int is = 0; is < 4; ++is){
            int r = rw + is*32;
            int pc = g8 ^ (r & 7);
            *(uint4*)(ldsA + r*128 + pc*16) = va[is];
            *(uint4*)(ldsB + r*128 + pc*16) = vb[is];
        }
        __syncthreads();
        if (ks < 4){
            int k0 = (ks + 1)*64;
            #pragma unroll
            for (int is = 0; is < 4; ++is){
                int r = rw + is*32;
                int ar = row0 + r; if (ar > NP-1) ar = NP-1;
                int br = col0 + r; if (br > NP-1) br = NP-1;
                va[is] = *(const uint4*)(A + (size_t)ar*DP + k0 + g8*8);
                vb[is] = *(const uint4*)(B + (size_t)br*DP + k0 + g8*8);
            }
        }
        f16x8 av[2][4], bv[2][4];
        #pragma unroll
        for (int ksl = 0; ksl < 2; ++ksl){
            int lc = ksl*4 + cq;
            int pc = (lc ^ (lr & 7))*16;
            #pragma unroll
            for (int mi = 0; mi < 4; ++mi)
                av[ksl][mi] = *(const f16x8*)(ldsA + (wm + mi*16 + lr)*128 + pc);
            #pragma unroll
            for (int ni = 0; ni < 4; ++ni)
                bv[ksl][ni] = *(const f16x8*)(ldsB + (wn + ni*16 + lr)*128 + pc);
        }
        #pragma unroll
        for (int ksl = 0; ksl < 2; ++ksl)
            #pragma unroll
            for (int mi = 0; mi < 4; ++mi)
                #pragma unroll
                for (int ni = 0; ni < 4; ++ni)
                    acc[mi][ni] = __builtin_amdgcn_mfma_f32_16x16x32_f16(av[ksl][mi], bv[ksl][ni], acc[mi][ni], 0, 0, 0);
    }

    int cqe = lane >> 4;
    __syncthreads();
    #pragma unroll
    for (int mi = 0; mi < 4; ++mi)
        #pragma unroll
        for (int ni = 0; ni < 4; ++ni){
            int lcol = wn + ni*16 + lr;
            bool colok = (col0 + lcol) < NP;
            #pragma unroll
            for (int v = 0; v < 4; ++v){
                int lrow = wm + mi*16 + cqe*4 + v;
                ldsO[lrow*136 + lcol] = __float2half(colok ? acc[mi][ni][v]*SCALE2INV : PADVAL);
            }
        }
    __syncthreads();
    {
        __half* tileD = P + (size_t)(b*4 + kind)*TSZ + ((size_t)bx*12 + by)*TILE;
        #pragma unroll
        for (int it = 0; it < 8; ++it){
            int e = it*256 + tid;
            int r = e >> 4, q = e & 15;
            u32x4 vv = *(const u32x4*)(ldsO + r*136 + q*8);
            __builtin_nontemporal_store(vv, (u32x4*)(tileD + r*128 + q*8));
        }
    }
    if (kind == 0 || bx != by){
        __syncthreads();
        #pragma unroll
        for (int mi = 0; mi < 4; ++mi)
            #pragma unroll
            for (int ni = 0; ni < 4; ++ni){
                int trow = wn + ni*16 + lr;
                #pragma unroll
                for (int v = 0; v < 4; ++v){
                    int tcol = wm + mi*16 + cqe*4 + v;
                    bool rowok = (row0 + tcol) < NP;
                    ldsO[trow*136 + tcol] = __float2half(rowok ? acc[mi][ni][v]*SCALE2INV : PADVAL);
                }
            }
        __syncthreads();
        int slotT = (kind == 0) ? 1 : kind;
        __half* tileT = P + (size_t)(b*4 + slotT)*TSZ + ((size_t)by*12 + bx)*TILE;
        #pragma unroll
        for (int it = 0; it < 8; ++it){
            int e = it*256 + tid;
            int r = e >> 4, q = e & 15;
            u32x4 vv = *(const u32x4*)(ldsO + r*136 + q*8);
            __builtin_nontemporal_store(vv, (u32x4*)(tileT + r*128 + q*8));
        }
    }
}

// ---- persistent Sinkhorn: 12 groups x 8 blocks x 1024 threads ----
__device__ __forceinline__ void groupbar(int* slot, int gsz){
    __syncthreads();
    if (threadIdx.x == 0){
        __hip_atomic_fetch_add(slot, 1, __ATOMIC_RELEASE, __HIP_MEMORY_SCOPE_AGENT);
        while (__hip_atomic_load(slot, __ATOMIC_ACQUIRE, __HIP_MEMORY_SCOPE_AGENT) < gsz)
            __builtin_amdgcn_s_sleep(1);
    }
    __syncthreads();
}

__device__ __forceinline__ void loadvec(const float* __restrict__ v, float4* A0, float4* A1, int lane){
    const float4* a4 = (const float4*)v;
    #pragma unroll
    for (int it = 0; it < 3; ++it){
        int c = lane + it*64, tt = c >> 4, q = c & 15;
        A0[it] = a4[tt*32 + q*2];
        A1[it] = a4[tt*32 + q*2 + 1];
    }
}

__device__ __forceinline__ void loadrow(const __half* __restrict__ rowb, int lane, uint4* pk){
    #pragma unroll
    for (int it = 0; it < 3; ++it){
        int c = lane + it*64, tt = c >> 4, q = c & 15;
        pk[it] = *(const uint4*)(rowb + (size_t)tt*TILE + q*8);
    }
}

__device__ __forceinline__ float redrow(const uint4* pk, const float4* A0, const float4* A1, int lane){
    float m = 3.0e38f;
    #pragma unroll
    for (int it = 0; it < 3; ++it){
        float2 c0 = __half22float2(*(const __half2*)&pk[it].x);
        float2 c1 = __half22float2(*(const __half2*)&pk[it].y);
        float2 c2 = __half22float2(*(const __half2*)&pk[it].z);
        float2 c3 = __half22float2(*(const __half2*)&pk[it].w);
        m = fminf(m, fminf(fminf(A0[it].x - c0.x, A0[it].y - c0.y), fminf(A0[it].z - c1.x, A0[it].w - c1.y)));
        m = fminf(m, fminf(fminf(A1[it].x - c2.x, A1[it].y - c2.y), fminf(A1[it].z - c3.x, A1[it].w - c3.y)));
    }
    #pragma unroll
    for (int o = 1; o < 64; o <<= 1) m = fminf(m, __shfl_xor(m, o, 64));
    return m;
}

#define ROWPTR(PK, i) ((PK) + (size_t)((i) >> 7)*12*TILE + (size_t)((i) & 127)*128)

__global__ __launch_bounds__(1024, 2) void k_sink(const __half* __restrict__ P,
        float* __restrict__ fs, float* __restrict__ uvv,
        float* __restrict__ px0, float* __restrict__ px1,
        float* __restrict__ py0, float* __restrict__ py1,
        int* __restrict__ bars, int* __restrict__ flags){
    int tid = threadIdx.x;
    int lane = tid & 63;
    int wid = tid >> 6;             // 0..15
    int blk = (int)blockIdx.x;
    __shared__ int s_ch;
    float4 A0[3], A1[3];
    uint4 pk0[3], pk1[3];

    if (blk < 4*OTB){
        // ---------------- OT group (fs <-> u), batch b ----------------
        int b = blk / OTB, lb = blk - b*OTB;
        int gw = lb*16 + wid;
        const int NWV = OTB*16;     // 128 waves
        int* gbarp  = bars + b*64;
        int* gflagp = flags + b*64;
        const __half* P0 = P + (size_t)(b*4 + 0)*TSZ;
        const __half* P1 = P + (size_t)(b*4 + 1)*TSZ;
        float* fsb = fs + b*VSZ;
        float* uvb = uvv + b*VSZ;
        for (int t = 0; t < 30; ++t){
            // phase A: fs_i = -(min_j(u_j - P0_ij) + K)
            if (tid == 0) s_ch = 0;
            __syncthreads();
            {
                int ch = 0;
                loadvec(uvb, A0, A1, lane);
                for (int i = gw; i < NP; i += 2*NWV){
                    int i2 = i + NWV;
                    loadrow(ROWPTR(P0, i), lane, pk0);
                    if (i2 < NP) loadrow(ROWPTR(P0, i2), lane, pk1);
                    float m = redrow(pk0, A0, A1, lane);
                    if (lane == 0){
                        float nv = -(m + KADD);
                        if (fabsf(nv - fsb[i]) > FTHR) ch = 1;
                        fsb[i] = nv;
                    }
                    if (i2 < NP){
                        float m2 = redrow(pk1, A0, A1, lane);
                        if (lane == 0){
                            float nv = -(m2 + KADD);
                            if (fabsf(nv - fsb[i2]) > FTHR) ch = 1;
                            fsb[i2] = nv;
                        }
                    }
                }
                if (ch) s_ch = 1;
            }
            __syncthreads();
            if (tid == 0 && s_ch) atomicOr(&gflagp[2*t], 1);
            groupbar(&gbarp[2*t], OTB);
            // phase B: u_j = -(min_i(fs_i - P1_ji) + K)
            if (tid == 0) s_ch = 0;
            __syncthreads();
            {
                int ch = 0;
                loadvec(fsb, A0, A1, lane);
                for (int i = gw; i < NP; i += 2*NWV){
                    int i2 = i + NWV;
                    loadrow(ROWPTR(P1, i), lane, pk0);
                    if (i2 < NP) loadrow(ROWPTR(P1, i2), lane, pk1);
                    float m = redrow(pk0, A0, A1, lane);
                    if (lane == 0){
                        float nv = -(m + KADD);
                        if (fabsf(nv - uvb[i]) > FTHR) ch = 1;
                        uvb[i] = nv;
                    }
                    if (i2 < NP){
                        float m2 = redrow(pk1, A0, A1, lane);
                        if (lane == 0){
                            float nv = -(m2 + KADD);
                            if (fabsf(nv - uvb[i2]) > FTHR) ch = 1;
                            uvb[i2] = nv;
                        }
                    }
                }
                if (ch) s_ch = 1;
            }
            __syncthreads();
            if (tid == 0 && s_ch) atomicOr(&gflagp[2*t + 1], 1);
            groupbar(&gbarp[2*t + 1], OTB);
            int fA = __hip_atomic_load(&gflagp[2*t],     __ATOMIC_RELAXED, __HIP_MEMORY_SCOPE_AGENT);
            int fB = __hip_atomic_load(&gflagp[2*t + 1], __ATOMIC_RELAXED, __HIP_MEMORY_SCOPE_AGENT);
            if (fA == 0 && fB == 0) break;
        }
    } else {
        // ---------------- self group (psxx or psyy), ping-pong ----------------
        int sg = blk - 4*OTB;
        int g = sg / SELFB, lb = sg - g*SELFB;
        int gw = lb*16 + wid;
        const int NWV = SELFB*16;   // 128 waves
        int b = g >> 1, kind = 2 + (g & 1);
        float* bufA = ((g & 1) ? py0 : px0) + b*VSZ;
        float* bufB = ((g & 1) ? py1 : px1) + b*VSZ;
        int* gbarp  = bars + (4 + g)*64;
        int* gflagp = flags + (4 + g)*64;
        const __half* PK = P + (size_t)(b*4 + kind)*TSZ;
        for (int t = 0; t < 30; ++t){
            if (tid == 0) s_ch = 0;
            __syncthreads();
            {
                int ch = 0;
                loadvec(bufA, A0, A1, lane);
                for (int i = gw; i < NP; i += 2*NWV){
                    int i2 = i + NWV;
                    loadrow(ROWPTR(PK, i), lane, pk0);
                    if (i2 < NP) loadrow(ROWPTR(PK, i2), lane, pk1);
                    float m = redrow(pk0, A0, A1, lane);
                    if (lane == 0){
                        float ov = bufA[i];
                        float nv = 0.5f*(ov - m - KADD);
                        if (fabsf(nv - ov) > FTHR) ch = 1;
                        bufB[i] = nv;
                    }
                    if (i2 < NP){
                        float m2 = redrow(pk1, A0, A1, lane);
                        if (lane == 0){
                            float ov = bufA[i2];
                            float nv = 0.5f*(ov - m2 - KADD);
                            if (fabsf(nv - ov) > FTHR) ch = 1;
                            bufB[i2] = nv;
                        }
                    }
                }
                if (ch) s_ch = 1;
            }
            __syncthreads();
            if (tid == 0 && s_ch) atomicOr(&gflagp[t], 1);
            groupbar(&gbarp[t], SELFB);
            int fC = __hip_atomic_load(&gflagp[t], __ATOMIC_RELAXED, __HIP_MEMORY_SCOPE_AGENT);
            if (fC == 0) break;              // frozen: |bufB - bufA| <= FTHR everywhere
            { float* tmp = bufA; bufA = bufB; bufB = tmp; }
        }
        // 30 full iters: last write lands in px0/py0; frozen-break: buffers equal within FTHR.
    }
}

// S = (4/1500) * sum_b,i (psxx + psyy - fs - u)
__global__ void k_final(const float* __restrict__ fs, const float* __restrict__ u,
                        const float* __restrict__ psxx, const float* __restrict__ psyy,
                        float* __restrict__ out){
    __shared__ double red[256];
    double s = 0.0;
    for (int t = threadIdx.x; t < NB*NP; t += 256){
        int b = t / NP, i = t - b*NP; int o = b*VSZ + i;
        s += (double)psxx[o] + (double)psyy[o] - (double)fs[o] - (double)u[o];
    }
    red[threadIdx.x] = s; __syncthreads();
    for (int w = 128; w > 0; w >>= 1){
        if (threadIdx.x < w) red[threadIdx.x] += red[threadIdx.x + w];
        __syncthreads();
    }
    if (threadIdx.x == 0) out[0] = (float)(red[0] * (4.0/1500.0));
}

extern "C" void kernel_launch(void* const* d_in, const int* in_sizes, int n_in,
                              void* d_out, int out_size, void* d_ws, size_t ws_size,
                              hipStream_t stream) {
    const float* x = (const float*)d_in[0];
    const float* y = (const float*)d_in[1];
    float* out = (float*)d_out;

    __half* pxh = (__half*)d_ws;                       // NB*NP*DP halfs
    __half* pyh = pxh + (size_t)NB*NP*DP;
    float* csx = (float*)(pyh + (size_t)NB*NP*DP);
    float* csy = csx + NB*DD;
    float* fs  = csy + NB*DD;
    float* uv  = fs + NB*VSZ;
    float* px0 = uv + NB*VSZ;
    float* px1 = px0 + NB*VSZ;
    float* py0 = px1 + NB*VSZ;
    float* py1 = py0 + NB*VSZ;
    int* bars  = (int*)(py1 + NB*VSZ);                 // 12*64 ints
    int* flags = bars + 12*64;                         // 12*64 ints
    float* partial = (float*)(flags + 12*64);          // 12*NB*2*DD floats
    float* smallEnd = partial + (size_t)12*NB*2*DD;
    size_t pOff = (((size_t)((char*)smallEnd - (char*)d_ws)) + 255) & ~(size_t)255;
    __half* P = (__half*)((char*)d_ws + pOff);         // 16*TSZ halfs = 75.5 MB

    int nzero = (int)(((float*)(flags + 12*64)) - csx);
    k_zero<<<(nzero + 255)/256, 256, 0, stream>>>(csx, nzero);

    k_colsum_p1<<<dim3(12, NB, 2), 256, 0, stream>>>(x, y, partial);
    k_colsum_p2<<<10, 256, 0, stream>>>(partial, csx, csy);

    k_normrow<<<3000, 256, 0, stream>>>(x, y, csx, csy, pxh, pyh, px0, uv, py0);

    k_gemm_mfma<<<dim3(12, 12, 12), 256, 0, stream>>>(pxh, pyh, P);

    k_sink<<<4*OTB + 8*SELFB, 1024, 0, stream>>>(P, fs, uv, px0, px1, py0, py1, bars, flags);

    k_final<<<1, 256, 0, stream>>>(fs, uv, px0, py0, out);
}